// Round 9
// baseline (1796.668 us; speedup 1.0000x reference)
//
#include <hip/hip_runtime.h>
#include <stdint.h>

#define NB 8
#define NC 2048
#define ND 768
#define CD (NC * ND)  // 1572864
#define EPSV 1e-5f

typedef _Float16 f16;
typedef f16 f16x2 __attribute__((ext_vector_type(2)));
typedef f16 f16x8 __attribute__((ext_vector_type(8)));
typedef float f32x4 __attribute__((ext_vector_type(4)));
typedef unsigned short u16;
typedef unsigned int u32;
typedef u32 u32x2 __attribute__((ext_vector_type(2)));
typedef u32 u32x4 __attribute__((ext_vector_type(4)));

__device__ __forceinline__ u16 f2h(float f) {
  return __builtin_bit_cast(u16, (f16)f);  // v_cvt_f16_f32, RNE
}
__device__ __forceinline__ u32 pack2(float a, float b) {
  f16x2 h = {(f16)a, (f16)b};
  return __builtin_bit_cast(u32, h);
}

__device__ __forceinline__ float wave_sum(float v) {
#pragma unroll
  for (int o = 32; o > 0; o >>= 1) v += __shfl_down(v, o);
  return v;
}
__device__ __forceinline__ float wave_max(float v) {
#pragma unroll
  for (int o = 32; o > 0; o >>= 1) v = fmaxf(v, __shfl_down(v, o));
  return v;
}

// ---------------- LayerNorm over [C,D] per batch ----------------
__global__ __launch_bounds__(256) void ln_stats(const float* __restrict__ x,
                                                float* __restrict__ stats) {
  const int b = blockIdx.y;
  const float4* xb = (const float4*)(x + (size_t)b * CD);
  const int base = blockIdx.x * 6144;
  float s1 = 0.f, s2 = 0.f;
  for (int i = threadIdx.x; i < 6144; i += 256) {
    float4 v = xb[base + i];
    s1 += (v.x + v.y) + (v.z + v.w);
    s2 += (v.x * v.x + v.y * v.y) + (v.z * v.z + v.w * v.w);
  }
  s1 = wave_sum(s1);
  s2 = wave_sum(s2);
  __shared__ float r1[4], r2[4];
  const int lane = threadIdx.x & 63, w = threadIdx.x >> 6;
  if (lane == 0) { r1[w] = s1; r2[w] = s2; }
  __syncthreads();
  if (threadIdx.x == 0) {
    atomicAdd(&stats[b * 2], (r1[0] + r1[1]) + (r1[2] + r1[3]));
    atomicAdd(&stats[b * 2 + 1], (r2[0] + r2[1]) + (r2[2] + r2[3]));
  }
}

__global__ __launch_bounds__(256) void ln_apply(const float* __restrict__ x,
                                                const float* __restrict__ stats,
                                                u16* __restrict__ xn) {
  const size_t i = ((size_t)blockIdx.x * 256 + threadIdx.x) * 8;
  const int b = (int)(i / CD);
  const float mean = stats[b * 2] * (1.f / CD);
  const float var = stats[b * 2 + 1] * (1.f / CD) - mean * mean;
  const float rstd = rsqrtf(var + EPSV);
  const float4 v0 = *(const float4*)(x + i);
  const float4 v1 = *(const float4*)(x + i + 4);
  u32x4 p;
  p.x = pack2((v0.x - mean) * rstd, (v0.y - mean) * rstd);
  p.y = pack2((v0.z - mean) * rstd, (v0.w - mean) * rstd);
  p.z = pack2((v1.x - mean) * rstd, (v1.y - mean) * rstd);
  p.w = pack2((v1.z - mean) * rstd, (v1.w - mean) * rstd);
  *(u32x4*)(xn + i) = p;
}

__global__ __launch_bounds__(256) void cast_w(const float* __restrict__ Wk,
                                              const float* __restrict__ Wq,
                                              const float* __restrict__ Wv,
                                              u16* __restrict__ Wb) {
  const size_t i = ((size_t)blockIdx.x * 256 + threadIdx.x) * 8;
  const size_t WSZ = (size_t)ND * ND;
  const float* src;
  size_t off;
  if (i < WSZ) { src = Wk; off = i; }
  else if (i < 2 * WSZ) { src = Wq; off = i - WSZ; }
  else { src = Wv; off = i - 2 * WSZ; }
  const float4 v0 = *(const float4*)(src + off);
  const float4 v1 = *(const float4*)(src + off + 4);
  u32x4 p;
  p.x = pack2(v0.x, v0.y);
  p.y = pack2(v0.z, v0.w);
  p.z = pack2(v1.x, v1.y);
  p.w = pack2(v1.z, v1.w);
  *(u32x4*)(Wb + i) = p;
}

// ======== 256x256-tile, BK=32-step, 8-wave, double-buffered GEMM core (NT) ========
// 64 KiB LDS -> 2 blocks/CU (cross-block overlap hides barrier/vmcnt drains).
// LDS chunk: [128 rows][4 slots of 16B], slot swizzled s ^ ((rl>>1)&3); chunk = rowhalf.
__device__ __forceinline__ void stage_chunk(u16* dst, const u16* src, int ld, int tid) {
  const int rl = tid >> 2;
  const int sc = (tid & 3) ^ ((tid >> 3) & 3);  // inverse swizzle on global source
  const u16* gp = src + (size_t)rl * ld + sc * 8;
  __builtin_amdgcn_global_load_lds(
      (const __attribute__((address_space(1))) void*)gp,
      (__attribute__((address_space(3))) void*)(dst + tid * 8), 16, 0, 0);
}

__device__ __forceinline__ void mf16(f32x4 acc[8][4], int mb, const f16x8 a[4],
                                     const f16x8 b[4]) {
#pragma unroll
  for (int m = 0; m < 4; ++m)
#pragma unroll
    for (int n = 0; n < 4; ++n)
      acc[mb + m][n] =
          __builtin_amdgcn_mfma_f32_16x16x32_f16(a[m], b[n], acc[mb + m][n], 0, 0, 0);
}

// Per-wave C: rows (mm>>2)*128 + wr*64 + (mm&3)*16 + (lane>>4)*4 + q,
//            cols (nn>>1)*128 + wc*32 + (nn&1)*16 + (lane&15).
__device__ __forceinline__ void gemm256(const u16* __restrict__ A, int lda,
                                        const u16* __restrict__ B, int ldb, int nk32,
                                        u16 (*lds)[2][2][4096], int tid,
                                        f32x4 acc[8][4]) {
  const int lane = tid & 63;
  const int wc = (tid >> 6) & 3;
  const int wr = (tid >> 8) & 1;
  const int fr = lane & 15;
  const int SL = (lane >> 4) ^ ((lane >> 1) & 3);  // swizzled 16B-slot
  int aoff[4], boff[4];
#pragma unroll
  for (int m = 0; m < 4; ++m) aoff[m] = (wr * 64 + m * 16 + fr) * 32 + SL * 8;
#pragma unroll
  for (int n = 0; n < 4; ++n) boff[n] = (wc * 32 + (n & 1) * 16 + fr) * 32 + SL * 8;

#define STG(BUF, S)                                                           \
  do {                                                                        \
    const u16* sa_ = A + (size_t)(S) * 32;                                    \
    stage_chunk(&lds[BUF][0][0][0], sa_, lda, tid);                           \
    stage_chunk(&lds[BUF][0][1][0], sa_ + (size_t)128 * lda, lda, tid);       \
    const u16* sb_ = B + (size_t)(S) * 32;                                    \
    stage_chunk(&lds[BUF][1][0][0], sb_, ldb, tid);                           \
    stage_chunk(&lds[BUF][1][1][0], sb_ + (size_t)128 * ldb, ldb, tid);       \
  } while (0)

  STG(0, 0);  // prologue: step 0 -> buf 0 (4 loads outstanding)
  for (int s = 0; s < nk32; ++s) {
    const int cur = s & 1, nb = cur ^ 1;
    const bool pre = (s + 1 < nk32);
    // loads for step s were issued one full step ago (~>1.2k cyc) -> drain is cheap
    asm volatile("s_waitcnt vmcnt(0)" ::: "memory");
    __builtin_amdgcn_s_barrier();  // also guarantees all waves done READING buf nb
    __builtin_amdgcn_sched_barrier(0);
    if (pre) STG(nb, s + 1);  // issue-after-barrier: WAR-safe staging
    f16x8 a0[4], a1[4], b[4];
#pragma unroll
    for (int m = 0; m < 4; ++m) a0[m] = *(const f16x8*)&lds[cur][0][0][aoff[m]];
#pragma unroll
    for (int m = 0; m < 4; ++m) a1[m] = *(const f16x8*)&lds[cur][0][1][aoff[m]];
    b[0] = *(const f16x8*)&lds[cur][1][0][boff[0]];
    b[1] = *(const f16x8*)&lds[cur][1][0][boff[1]];
    b[2] = *(const f16x8*)&lds[cur][1][1][boff[2]];
    b[3] = *(const f16x8*)&lds[cur][1][1][boff[3]];
    __builtin_amdgcn_s_setprio(1);
    mf16(acc, 0, a0, b);
    mf16(acc, 4, a1, b);
    __builtin_amdgcn_s_setprio(0);
  }
#undef STG
}

// z<2: SWAPPED (A=W rows d, B=xn rows c) -> q packs along d -> u32x2 stores into K/Q[c][d].
// z=2: A=xn rows c, B=Wv rows d -> q packs along c -> u32x2 stores into Vt[b][d][c].
__global__ __launch_bounds__(512, 4) void gemm_proj(const u16* __restrict__ xn,
                                                    const u16* __restrict__ Wb,
                                                    u16* __restrict__ Kb,
                                                    u16* __restrict__ Qb,
                                                    u16* __restrict__ Vt) {
  __shared__ u16 lds[2][2][2][4096];
  const int tid = threadIdx.x;
  const int xblk = blockIdx.x * 256;  // xn rows (token c)
  const int wblk = blockIdx.y * 256;  // W rows (out-dim d)
  const int z = blockIdx.z;
  f32x4 acc[8][4] = {};
  const int lane = tid & 63, wc = (tid >> 6) & 3, wr = (tid >> 8) & 1;
  if (z < 2) {
    gemm256(Wb + (size_t)z * ND * ND + (size_t)wblk * ND, ND, xn + (size_t)xblk * ND, ND,
            ND / 32, lds, tid, acc);
    u16* O = (z == 0) ? Kb : Qb;
#pragma unroll
    for (int mm = 0; mm < 8; ++mm) {
      const int d = wblk + (mm >> 2) * 128 + wr * 64 + (mm & 3) * 16 + ((lane >> 4) << 2);
#pragma unroll
      for (int nn = 0; nn < 4; ++nn) {
        const int c = xblk + (nn >> 1) * 128 + wc * 32 + (nn & 1) * 16 + (lane & 15);
        u32x2 p;
        p.x = pack2(acc[mm][nn][0], acc[mm][nn][1]);
        p.y = pack2(acc[mm][nn][2], acc[mm][nn][3]);
        *(u32x2*)(O + (size_t)c * ND + d) = p;
      }
    }
  } else {
    gemm256(xn + (size_t)xblk * ND, ND, Wb + (size_t)2 * ND * ND + (size_t)wblk * ND, ND,
            ND / 32, lds, tid, acc);
#pragma unroll
    for (int mm = 0; mm < 8; ++mm) {
      const int r = xblk + (mm >> 2) * 128 + wr * 64 + (mm & 3) * 16 + ((lane >> 4) << 2);
      const int bb = r >> 11;
      const int cc = r & 2047;
#pragma unroll
      for (int nn = 0; nn < 4; ++nn) {
        const int d = wblk + (nn >> 1) * 128 + wc * 32 + (nn & 1) * 16 + (lane & 15);
        u32x2 p;
        p.x = pack2(acc[mm][nn][0], acc[mm][nn][1]);
        p.y = pack2(acc[mm][nn][2], acc[mm][nn][3]);
        *(u32x2*)(Vt + ((size_t)bb * ND + d) * NC + cc) = p;
      }
    }
  }
}

// SWAPPED: A=K rows j, B=Q rows i -> q packs along j -> u32x2 f16 stores into S[i][j].
__global__ __launch_bounds__(512, 4) void gemm_qk(const u16* __restrict__ Qb,
                                                  const u16* __restrict__ Kb,
                                                  u16* __restrict__ S) {
  __shared__ u16 lds[2][2][2][4096];
  const int tid = threadIdx.x;
  const int bz = blockIdx.z;
  const int iblk = blockIdx.x * 256, jblk = blockIdx.y * 256;
  f32x4 acc[8][4] = {};
  gemm256(Kb + ((size_t)bz * NC + jblk) * ND, ND, Qb + ((size_t)bz * NC + iblk) * ND, ND,
          ND / 32, lds, tid, acc);
  u16* Sb = S + (size_t)bz * NC * NC;
  const int lane = tid & 63, wc = (tid >> 6) & 3, wr = (tid >> 8) & 1;
#pragma unroll
  for (int mm = 0; mm < 8; ++mm) {
    const int j = jblk + (mm >> 2) * 128 + wr * 64 + (mm & 3) * 16 + ((lane >> 4) << 2);
#pragma unroll
    for (int nn = 0; nn < 4; ++nn) {
      const int i = iblk + (nn >> 1) * 128 + wc * 32 + (nn & 1) * 16 + (lane & 15);
      u32x2 p;
      p.x = pack2(acc[mm][nn][0], acc[mm][nn][1]);
      p.y = pack2(acc[mm][nn][2], acc[mm][nn][3]);
      *(u32x2*)(Sb + (size_t)i * NC + j) = p;
    }
  }
}

// softmax over each row of S (2048 f16); write f16 att in-place
__global__ __launch_bounds__(256) void softmax_rows(u16* __restrict__ S) {
  u16* Sr = S + (size_t)blockIdx.x * NC;
  const int t = threadIdx.x;
  const f16x8 v = *(const f16x8*)(Sr + t * 8);
  float f[8];
#pragma unroll
  for (int j = 0; j < 8; ++j) f[j] = (float)v[j];
  float mv = fmaxf(fmaxf(fmaxf(f[0], f[1]), fmaxf(f[2], f[3])),
                   fmaxf(fmaxf(f[4], f[5]), fmaxf(f[6], f[7])));
  mv = wave_max(mv);
  __shared__ float rm[4], rs[4];
  const int lane = t & 63, w = t >> 6;
  if (lane == 0) rm[w] = mv;
  __syncthreads();
  const float bm = fmaxf(fmaxf(rm[0], rm[1]), fmaxf(rm[2], rm[3]));
  float e[8];
  float s = 0.f;
#pragma unroll
  for (int j = 0; j < 8; ++j) { e[j] = __expf(f[j] - bm); s += e[j]; }
  s = wave_sum(s);
  if (lane == 0) rs[w] = s;
  __syncthreads();
  const float inv = 1.f / ((rs[0] + rs[1]) + (rs[2] + rs[3]));
  u32x4 p;
  p.x = pack2(e[0] * inv, e[1] * inv);
  p.y = pack2(e[2] * inv, e[3] * inv);
  p.z = pack2(e[4] * inv, e[5] * inv);
  p.w = pack2(e[6] * inv, e[7] * inv);
  *(u32x4*)(Sr + t * 8) = p;
}

// SWAPPED: A=Vt rows d, B=att rows i -> q packs along d -> float4 stores into out[i][d].
__global__ __launch_bounds__(512, 4) void gemm_av(const u16* __restrict__ att,
                                                  const u16* __restrict__ Vt,
                                                  float* __restrict__ out) {
  __shared__ u16 lds[2][2][2][4096];
  const int tid = threadIdx.x;
  const int bz = blockIdx.z;
  const int iblk = blockIdx.x * 256, dblk = blockIdx.y * 256;
  f32x4 acc[8][4] = {};
  gemm256(Vt + ((size_t)bz * ND + dblk) * NC, NC, att + ((size_t)bz * NC + iblk) * NC, NC,
          NC / 32, lds, tid, acc);
  float* Ob = out + (size_t)bz * CD;
  const int lane = tid & 63, wc = (tid >> 6) & 3, wr = (tid >> 8) & 1;
#pragma unroll
  for (int mm = 0; mm < 8; ++mm) {
    const int d = dblk + (mm >> 2) * 128 + wr * 64 + (mm & 3) * 16 + ((lane >> 4) << 2);
#pragma unroll
    for (int nn = 0; nn < 4; ++nn) {
      const int i = iblk + (nn >> 1) * 128 + wc * 32 + (nn & 1) * 16 + (lane & 15);
      *(f32x4*)(Ob + (size_t)i * ND + d) = acc[mm][nn];
    }
  }
}

extern "C" void kernel_launch(void* const* d_in, const int* in_sizes, int n_in,
                              void* d_out, int out_size, void* d_ws, size_t ws_size,
                              hipStream_t stream) {
  (void)in_sizes; (void)n_in; (void)out_size; (void)ws_size;
  const float* x = (const float*)d_in[0];
  const float* Wk = (const float*)d_in[1];
  const float* Wq = (const float*)d_in[2];
  const float* Wv = (const float*)d_in[3];
  char* ws = (char*)d_ws;
  float* stats = (float*)ws;                    //        64 B
  u16* xn = (u16*)(ws + 256);                   //  25165824
  u16* Wb = (u16*)(ws + 25166080);              //   3538944
  u16* Qb = (u16*)(ws + 28705024);              //  25165824
  u16* Kb = (u16*)(ws + 53870848);              //  25165824
  u16* Vt = (u16*)(ws + 79036672);              //  25165824
  u16* S = (u16*)(ws + 104202496);              //  67108864 (end 171311360)
  float* out = (float*)d_out;

  hipMemsetAsync(stats, 0, 64, stream);
  ln_stats<<<dim3(64, 8), 256, 0, stream>>>(x, stats);
  ln_apply<<<6144, 256, 0, stream>>>(x, stats, xn);
  cast_w<<<864, 256, 0, stream>>>(Wk, Wq, Wv, Wb);
  gemm_proj<<<dim3(64, 3, 3), 512, 0, stream>>>(xn, Wb, Kb, Qb, Vt);
  gemm_qk<<<dim3(8, 8, 8), 512, 0, stream>>>(Qb, Kb, S);
  softmax_rows<<<16384, 256, 0, stream>>>(S);
  gemm_av<<<dim3(8, 3, 8), 512, 0, stream>>>(S, Vt, out);
}